// Round 12
// baseline (53.999 us; speedup 1.0000x reference)
//
#include <hip/hip_runtime.h>
#include <hip/hip_bf16.h>
#include <math.h>

// Problem constants (B=4, T=2048, D=1024, H=64), fp32 in/out.
#define Bb   4
#define Tlen 2048
#define Dd   1024
#define Hh   64
#define NROWS 8192      // B*T
#define NQ   32         // q-tiles of 64 rows per batch
#define MAXCH 8         // max key-chunks per (b,qt)

typedef short bf16x8 __attribute__((ext_vector_type(8)));
typedef float f32x4  __attribute__((ext_vector_type(4)));

__device__ __forceinline__ unsigned short f2b(float f) {
    unsigned u = __float_as_uint(f);
    unsigned r = u + 0x7FFFu + ((u >> 16) & 1u);   // RNE
    return (unsigned short)(r >> 16);
}
__device__ __forceinline__ unsigned pk2(float a, float b) {   // 2xf32 -> packed bf16x2 (RNE)
    __hip_bfloat162 h = __float22bfloat162_rn(make_float2(a, b));
    return *reinterpret_cast<unsigned*>(&h);
}

// ---------------- Kernel 0: W -> MFMA B-fragment layout ----------------
__global__ __launch_bounds__(256) void wtrans_kernel(
    const float* __restrict__ Wq, const float* __restrict__ Wk,
    const float* __restrict__ Wv, unsigned short* __restrict__ wfrag)
{
    const int s = blockIdx.x * 256 + threadIdx.x;    // 0..24575
    const int f   = s / 768;
    const int rem = s % 768;
    const int nb  = rem >> 6;
    const int lane = rem & 63;
    const int g = lane >> 4, qr = lane & 15;
    const int n = nb * 16 + qr;
    const int wsel = n >> 6, h = n & 63;
    const float* W = (wsel == 0) ? Wq : (wsel == 1) ? Wk : Wv;
    const int k0 = (f >> 1) * 64 + (f & 1) * 32 + g * 8;
    unsigned short tmp[8];
    #pragma unroll
    for (int j = 0; j < 8; ++j) tmp[j] = f2b(W[(size_t)(k0 + j) * Hh + h]);
    *(bf16x8*)(wfrag + (size_t)s * 8) = *(const bf16x8*)tmp;
}

// ---------------- Kernel 1: fused QKV projection (round-5 hybrid, best measured) ----------------
__global__ __launch_bounds__(256) void proj_kernel(
    const float* __restrict__ x, const unsigned short* __restrict__ wfrag,
    unsigned short* __restrict__ qw, unsigned short* __restrict__ kw,
    unsigned short* __restrict__ vw)
{
    __shared__ unsigned short xs[2][32 * 64];

    const int rb   = blockIdx.x * 32;
    const int tid  = threadIdx.x;
    const int wv   = tid >> 6;
    const int lane = tid & 63;
    const int qr   = lane & 15;
    const int g    = lane >> 4;

    const int xr = tid >> 3, xc8 = tid & 7;
    const float* xg0 = x + (size_t)(rb + xr) * Dd + xc8 * 8;

    const unsigned short* wp = wfrag + ((size_t)(wv * 3) * 64 + lane) * 8;

    f32x4 acc[6] = {};   // [mf][nf]

    float4 px0 = *(const float4*)(xg0 + 0);
    float4 px1 = *(const float4*)(xg0 + 4);

    #pragma unroll
    for (int t = 0; t < 16; ++t) {
        const int cur = t & 1;
        {
            union { unsigned u[4]; bf16x8 v; } p8;
            p8.u[0] = pk2(px0.x, px0.y);
            p8.u[1] = pk2(px0.z, px0.w);
            p8.u[2] = pk2(px1.x, px1.y);
            p8.u[3] = pk2(px1.z, px1.w);
            *(bf16x8*)(&xs[cur][xr * 64 + ((xc8 ^ (xr & 7)) << 3)]) = p8.v;
        }
        __syncthreads();

        if (t < 15) {
            px0 = *(const float4*)(xg0 + (t + 1) * 64 + 0);
            px1 = *(const float4*)(xg0 + (t + 1) * 64 + 4);
        }

        #pragma unroll
        for (int ks = 0; ks < 2; ++ks) {
            const int f = t * 2 + ks;
            bf16x8 b0 = *(const bf16x8*)(wp + (size_t)(f * 12 + 0) * 512);
            bf16x8 b1 = *(const bf16x8*)(wp + (size_t)(f * 12 + 1) * 512);
            bf16x8 b2 = *(const bf16x8*)(wp + (size_t)(f * 12 + 2) * 512);
            #pragma unroll
            for (int mf = 0; mf < 2; ++mf) {
                const int arow = mf * 16 + qr;
                const bf16x8 a = *(const bf16x8*)(
                    &xs[cur][arow * 64 + (((ks * 4 + g) ^ (arow & 7)) << 3)]);
                acc[mf * 3 + 0] = __builtin_amdgcn_mfma_f32_16x16x32_bf16(a, b0, acc[mf * 3 + 0], 0, 0, 0);
                acc[mf * 3 + 1] = __builtin_amdgcn_mfma_f32_16x16x32_bf16(a, b1, acc[mf * 3 + 1], 0, 0, 0);
                acc[mf * 3 + 2] = __builtin_amdgcn_mfma_f32_16x16x32_bf16(a, b2, acc[mf * 3 + 2], 0, 0, 0);
            }
        }
        __syncthreads();
    }

    #pragma unroll
    for (int mf = 0; mf < 2; ++mf) {
        #pragma unroll
        for (int nf = 0; nf < 3; ++nf) {
            const int n = wv * 48 + nf * 16 + qr;
            const int wsel = n >> 6, h = n & 63;
            unsigned short* out = (wsel == 0) ? qw : (wsel == 1) ? kw : vw;
            const f32x4 ov = acc[mf * 3 + nf];
            #pragma unroll
            for (int r = 0; r < 4; ++r)
                out[(size_t)(rb + mf * 16 + 4 * g + r) * Hh + h] = f2b(ov[r]);
        }
    }
}

// ---------------- Kernel 2: flash attention partials, KVBLK=64, balanced chunks ----------------
// grid (NQ, MAXCH, B); block (qt, ci, b) covers 64-key tiles [ci*C, min(ntk,(ci+1)*C))
// where ntk = qt+1, nch = min(8, ceil(ntk/2)), C = ceil(ntk/nch). Blocks with
// ci >= ceil(ntk/C) exit. Per tile: 16 MFMA; softmax/shuffle chain paid per 64
// keys (was per 32). K/V register-prefetched one tile ahead.
#define KXSTR 72
#define VTSTR 72
__global__ __launch_bounds__(256) void attn_kernel(
    const unsigned short* __restrict__ qw, const unsigned short* __restrict__ kw,
    const unsigned short* __restrict__ vw,
    float* __restrict__ part_O, float* __restrict__ part_ml)
{
    __shared__ unsigned short ks_s[64 * KXSTR];
    __shared__ unsigned short vt_s[64 * VTSTR];

    const int qt = (NQ - 1) - blockIdx.x;   // big q-tiles dispatched first
    const int ci = blockIdx.y;
    const int b  = blockIdx.z;

    const int ntk = qt + 1;                        // causal 64-key tiles
    const int nch = min(MAXCH, (ntk + 1) >> 1);
    const int C   = (ntk + nch - 1) / nch;
    const int nuse = (ntk + C - 1) / C;
    if (ci >= nuse) return;
    const int t0 = ci * C;
    const int t1 = (ntk < t0 + C) ? ntk : (t0 + C);

    const int tid = threadIdx.x;
    const int wv = tid >> 6, lane = tid & 63;
    const int qr = lane & 15, g = lane >> 4;

    const size_t base = (size_t)b * Tlen * Hh;
    const int qrow = qt * 64 + wv * 16 + qr;

    const bf16x8 qf0 = *(const bf16x8*)(qw + base + (size_t)qrow * Hh + 8 * g);
    const bf16x8 qf1 = *(const bf16x8*)(qw + base + (size_t)qrow * Hh + 32 + 8 * g);

    f32x4 o[4] = {};
    float m = -INFINITY, l = 0.f;

    // staging: 2 items/thread, item -> (row 0..63, col-group 0..7)
    const int row_a = tid >> 3, cg_a = tid & 7;          // rows 0..31
    const int row_b = 32 + row_a, cg_b = cg_a;           // rows 32..63
    const unsigned short* kA = kw + base + (size_t)row_a * Hh + cg_a * 8;
    const unsigned short* kB = kw + base + (size_t)row_b * Hh + cg_b * 8;
    const unsigned short* vA = vw + base + (size_t)row_a * Hh + cg_a * 8;
    const unsigned short* vB = vw + base + (size_t)row_b * Hh + cg_b * 8;

    bf16x8 k8a, k8b, v8a, v8b;
    {
        const size_t off = (size_t)t0 * 64 * Hh;
        k8a = *(const bf16x8*)(kA + off);  k8b = *(const bf16x8*)(kB + off);
        v8a = *(const bf16x8*)(vA + off);  v8b = *(const bf16x8*)(vB + off);
    }

    for (int kt = t0; kt < t1; ++kt) {
        const int j0 = kt * 64;
        __syncthreads();                 // previous tile fully consumed
        // write prefetched K/V -> LDS (K row-swizzled; V transposed)
        *(bf16x8*)(&ks_s[row_a * KXSTR + ((cg_a ^ (row_a & 3)) << 3)]) = k8a;
        *(bf16x8*)(&ks_s[row_b * KXSTR + ((cg_b ^ (row_b & 3)) << 3)]) = k8b;
        #pragma unroll
        for (int u = 0; u < 8; ++u) {
            const int ca = cg_a * 8 + u;
            vt_s[ca * VTSTR + (((row_a >> 3) ^ (ca & 7)) << 3) + (row_a & 7)] =
                ((const unsigned short*)&v8a)[u];
            vt_s[ca * VTSTR + (((row_b >> 3) ^ (ca & 7)) << 3) + (row_b & 7)] =
                ((const unsigned short*)&v8b)[u];
        }
        __syncthreads();

        // issue next tile's loads (hidden under compute)
        if (kt + 1 < t1) {
            const size_t off = (size_t)(kt + 1) * 64 * Hh;
            k8a = *(const bf16x8*)(kA + off);  k8b = *(const bf16x8*)(kB + off);
            v8a = *(const bf16x8*)(vA + off);  v8b = *(const bf16x8*)(vB + off);
        }

        // S^T = K . Q^T : 4 j-frags x 2 k-steps
        f32x4 a[4] = {};
        #pragma unroll
        for (int jf = 0; jf < 4; ++jf) {
            const int row = jf * 16 + qr;
            const int sw = ((g ^ (row & 3)) << 3);
            bf16x8 kf = *(const bf16x8*)(&ks_s[row * KXSTR + sw]);
            a[jf] = __builtin_amdgcn_mfma_f32_16x16x32_bf16(kf, qf0, a[jf], 0, 0, 0);
            kf = *(const bf16x8*)(&ks_s[row * KXSTR + 32 + sw]);
            a[jf] = __builtin_amdgcn_mfma_f32_16x16x32_bf16(kf, qf1, a[jf], 0, 0, 0);
        }

        // masked scores + online softmax (lane owns q-row qr; j = jf*16+4g+r)
        float p[16];
        float tm = -INFINITY;
        #pragma unroll
        for (int jf = 0; jf < 4; ++jf) {
            #pragma unroll
            for (int r = 0; r < 4; ++r) {
                const int jg = j0 + jf * 16 + 4 * g + r;
                float s = a[jf][r] * 0.125f;
                s = (jg > qrow) ? -INFINITY : s;
                p[jf * 4 + r] = s;
                tm = fmaxf(tm, s);
            }
        }
        tm = fmaxf(tm, __shfl_xor(tm, 16));
        tm = fmaxf(tm, __shfl_xor(tm, 32));
        const float mnew  = fmaxf(m, tm);
        const float alpha = (m == -INFINITY) ? 0.f : __expf(m - mnew);
        float psum = 0.f;
        #pragma unroll
        for (int i = 0; i < 16; ++i) {
            const float pv = (p[i] == -INFINITY) ? 0.f : __expf(p[i] - mnew);
            p[i] = pv; psum += pv;
        }
        psum += __shfl_xor(psum, 16);
        psum += __shfl_xor(psum, 32);
        l = l * alpha + psum;
        m = mnew;

        // rescale O (o-rows are q = 4g+r)
        const float ar0 = __shfl(alpha, 4 * g + 0);
        const float ar1 = __shfl(alpha, 4 * g + 1);
        const float ar2 = __shfl(alpha, 4 * g + 2);
        const float ar3 = __shfl(alpha, 4 * g + 3);
        #pragma unroll
        for (int nf = 0; nf < 4; ++nf) {
            o[nf][0] *= ar0; o[nf][1] *= ar1; o[nf][2] *= ar2; o[nf][3] *= ar3;
        }

        // repack P (S^T layout) -> PV A-frags pa0 (j 0..31), pa1 (j 32..63)
        unsigned pw[8];
        #pragma unroll
        for (int jf = 0; jf < 4; ++jf) {
            pw[jf * 2 + 0] = f2b(p[jf * 4 + 0]) | ((unsigned)f2b(p[jf * 4 + 1]) << 16);
            pw[jf * 2 + 1] = f2b(p[jf * 4 + 2]) | ((unsigned)f2b(p[jf * 4 + 3]) << 16);
        }
        union PU { unsigned u[4]; bf16x8 v; } pl, ph;
        #pragma unroll
        for (int w = 0; w < 4; ++w) {
            const int src = 16 * ((g & 1) * 2 + (w >> 1)) + qr;
            const unsigned s0 = __shfl(pw[0 + (w & 1)], src);
            const unsigned s1 = __shfl(pw[2 + (w & 1)], src);
            const unsigned s2 = __shfl(pw[4 + (w & 1)], src);
            const unsigned s3 = __shfl(pw[6 + (w & 1)], src);
            pl.u[w] = (g >> 1) ? s1 : s0;
            ph.u[w] = (g >> 1) ? s3 : s2;
        }
        const bf16x8 pa0 = pl.v, pa1 = ph.v;

        // O += P . V  (V^T B-frags, 2 k-steps)
        #pragma unroll
        for (int nf = 0; nf < 4; ++nf) {
            const int c = nf * 16 + qr;
            bf16x8 vf = *(const bf16x8*)(&vt_s[c * VTSTR + (((0 + g) ^ (c & 7)) << 3)]);
            o[nf] = __builtin_amdgcn_mfma_f32_16x16x32_bf16(pa0, vf, o[nf], 0, 0, 0);
            vf = *(const bf16x8*)(&vt_s[c * VTSTR + (((4 + g) ^ (c & 7)) << 3)]);
            o[nf] = __builtin_amdgcn_mfma_f32_16x16x32_bf16(pa1, vf, o[nf], 0, 0, 0);
        }
    }

    // write partials (unnormalized O', m, l)
    const int blin = (b * NQ + qt) * MAXCH + ci;
    float* po = part_O + (size_t)blin * 4096;
    #pragma unroll
    for (int nf = 0; nf < 4; ++nf) {
        #pragma unroll
        for (int r = 0; r < 4; ++r)
            po[(size_t)(wv * 16 + 4 * g + r) * 64 + nf * 16 + qr] = o[nf][r];
    }
    if (g == 0) {
        part_ml[(size_t)blin * 128 + wv * 16 + qr]      = m;
        part_ml[(size_t)blin * 128 + 64 + wv * 16 + qr] = l;
    }
}

// ---------------- Kernel 3: merge partials (variable chunk count) ----------------
__global__ __launch_bounds__(256) void merge_kernel(
    const float* __restrict__ part_O, const float* __restrict__ part_ml,
    float* __restrict__ out)
{
    const int idx = blockIdx.x * 256 + threadIdx.x;   // 0 .. 524287
    const int row = idx >> 6;
    const int c   = idx & 63;
    const int b   = row >> 11;
    const int t   = row & 2047;
    const int qt  = t >> 6;
    const int qq  = t & 63;

    const int ntk = qt + 1;
    const int nch = min(MAXCH, (ntk + 1) >> 1);
    const int C   = (ntk + nch - 1) / nch;
    const int nuse = (ntk + C - 1) / C;
    const int bl0 = (b * NQ + qt) * MAXCH;

    float M = -INFINITY;
    for (int i = 0; i < nuse; ++i)
        M = fmaxf(M, part_ml[(size_t)(bl0 + i) * 128 + qq]);
    float num = 0.f, den = 0.f;
    for (int i = 0; i < nuse; ++i) {
        const float lvi = part_ml[(size_t)(bl0 + i) * 128 + 64 + qq];
        const float wgt = __expf(part_ml[(size_t)(bl0 + i) * 128 + qq] - M);
        num += wgt * part_O[(size_t)(bl0 + i) * 4096 + (size_t)qq * 64 + c];
        den += wgt * lvi;
    }
    out[(size_t)row * 64 + c] = num / den;
}

extern "C" void kernel_launch(void* const* d_in, const int* in_sizes, int n_in,
                              void* d_out, int out_size, void* d_ws, size_t ws_size,
                              hipStream_t stream) {
    const float* x  = (const float*)d_in[0];
    const float* Wq = (const float*)d_in[1];
    const float* Wk = (const float*)d_in[2];
    const float* Wv = (const float*)d_in[3];
    float* outp = (float*)d_out;

    unsigned short* wfrag = (unsigned short*)d_ws;      // 192*1024 bf16
    unsigned short* qw = wfrag + 192 * 1024;            // 8192*64 each
    unsigned short* kw = qw + NROWS * Hh;
    unsigned short* vw = kw + NROWS * Hh;
    float* part_O  = (float*)(vw + NROWS * Hh);         // (Bb*NQ*MAXCH) * 4096
    float* part_ml = part_O + (size_t)(Bb * NQ * MAXCH) * 4096;

    wtrans_kernel<<<dim3(96), 256, 0, stream>>>(Wq, Wk, Wv, wfrag);
    proj_kernel<<<dim3(NROWS / 32), 256, 0, stream>>>(x, wfrag, qw, kw, vw);
    attn_kernel<<<dim3(NQ, MAXCH, Bb), 256, 0, stream>>>(qw, kw, vw, part_O, part_ml);
    merge_kernel<<<dim3((NROWS * Hh) / 256), 256, 0, stream>>>(part_O, part_ml, outp);
}

// Round 13
// 48.524 us; speedup vs baseline: 1.1128x; 1.1128x over previous
//
#include <hip/hip_runtime.h>
#include <hip/hip_bf16.h>
#include <math.h>

// Problem constants (B=4, T=2048, D=1024, H=64), fp32 in/out.
#define Bb   4
#define Tlen 2048
#define Dd   1024
#define Hh   64
#define NROWS 8192      // B*T
#define NQ   32         // q-tiles of 64 rows per batch
#define NC   4          // flash-decoding split

typedef short bf16x8 __attribute__((ext_vector_type(8)));
typedef float f32x4  __attribute__((ext_vector_type(4)));

__device__ __forceinline__ unsigned short f2b(float f) {
    unsigned u = __float_as_uint(f);
    unsigned r = u + 0x7FFFu + ((u >> 16) & 1u);   // RNE
    return (unsigned short)(r >> 16);
}
__device__ __forceinline__ unsigned pk2(float a, float b) {   // 2xf32 -> packed bf16x2 (RNE)
    __hip_bfloat162 h = __float22bfloat162_rn(make_float2(a, b));
    return *reinterpret_cast<unsigned*>(&h);
}

// ---------------- Kernel 0: W -> MFMA B-fragment layout ----------------
__global__ __launch_bounds__(256) void wtrans_kernel(
    const float* __restrict__ Wq, const float* __restrict__ Wk,
    const float* __restrict__ Wv, unsigned short* __restrict__ wfrag)
{
    const int s = blockIdx.x * 256 + threadIdx.x;    // 0..24575
    const int f   = s / 768;
    const int rem = s % 768;
    const int nb  = rem >> 6;
    const int lane = rem & 63;
    const int g = lane >> 4, qr = lane & 15;
    const int n = nb * 16 + qr;
    const int wsel = n >> 6, h = n & 63;
    const float* W = (wsel == 0) ? Wq : (wsel == 1) ? Wk : Wv;
    const int k0 = (f >> 1) * 64 + (f & 1) * 32 + g * 8;
    unsigned short tmp[8];
    #pragma unroll
    for (int j = 0; j < 8; ++j) tmp[j] = f2b(W[(size_t)(k0 + j) * Hh + h]);
    *(bf16x8*)(wfrag + (size_t)s * 8) = *(const bf16x8*)tmp;
}

// ---------------- Kernel 1: QKV projection (round-5 base + W reg-prefetch) ----------------
// 256 blocks x 256 threads; block = 32 rows x 192 cols; wave = N-slice.
// x AND W fragments both register-prefetched one K-step ahead -> the in-step
// critical path is LDS reads + MFMA only (W L2 latency was ~600cy/step).
__global__ __launch_bounds__(256) void proj_kernel(
    const float* __restrict__ x, const unsigned short* __restrict__ wfrag,
    unsigned short* __restrict__ qw, unsigned short* __restrict__ kw,
    unsigned short* __restrict__ vw)
{
    __shared__ unsigned short xs[2][32 * 64];

    const int rb   = blockIdx.x * 32;
    const int tid  = threadIdx.x;
    const int wv   = tid >> 6;
    const int lane = tid & 63;
    const int qr   = lane & 15;
    const int g    = lane >> 4;

    const int xr = tid >> 3, xc8 = tid & 7;
    const float* xg0 = x + (size_t)(rb + xr) * Dd + xc8 * 8;

    const unsigned short* wp = wfrag + ((size_t)(wv * 3) * 64 + lane) * 8;

    f32x4 acc[6] = {};   // [mf][nf]

    float4 px0 = *(const float4*)(xg0 + 0);
    float4 px1 = *(const float4*)(xg0 + 4);

    // W prefetch for step 0 (f = 0,1)
    bf16x8 wr[6];
    #pragma unroll
    for (int ks = 0; ks < 2; ++ks)
        #pragma unroll
        for (int nf = 0; nf < 3; ++nf)
            wr[ks * 3 + nf] = *(const bf16x8*)(wp + (size_t)(ks * 12 + nf) * 512);

    #pragma unroll
    for (int t = 0; t < 16; ++t) {
        const int cur = t & 1;
        {   // stage x(t) from regs
            union { unsigned u[4]; bf16x8 v; } p8;
            p8.u[0] = pk2(px0.x, px0.y);
            p8.u[1] = pk2(px0.z, px0.w);
            p8.u[2] = pk2(px1.x, px1.y);
            p8.u[3] = pk2(px1.z, px1.w);
            *(bf16x8*)(&xs[cur][xr * 64 + ((xc8 ^ (xr & 7)) << 3)]) = p8.v;
        }
        __syncthreads();

        // issue x(t+1) and W(t+1) loads; they have a full step to land
        bf16x8 wn[6];
        if (t < 15) {
            px0 = *(const float4*)(xg0 + (t + 1) * 64 + 0);
            px1 = *(const float4*)(xg0 + (t + 1) * 64 + 4);
            const int fb = (t + 1) * 2;
            #pragma unroll
            for (int ks = 0; ks < 2; ++ks)
                #pragma unroll
                for (int nf = 0; nf < 3; ++nf)
                    wn[ks * 3 + nf] = *(const bf16x8*)(wp + (size_t)((fb + ks) * 12 + nf) * 512);
        }

        // compute step t from LDS + prefetched W regs
        #pragma unroll
        for (int ks = 0; ks < 2; ++ks) {
            #pragma unroll
            for (int mf = 0; mf < 2; ++mf) {
                const int arow = mf * 16 + qr;
                const bf16x8 a = *(const bf16x8*)(
                    &xs[cur][arow * 64 + (((ks * 4 + g) ^ (arow & 7)) << 3)]);
                acc[mf * 3 + 0] = __builtin_amdgcn_mfma_f32_16x16x32_bf16(a, wr[ks * 3 + 0], acc[mf * 3 + 0], 0, 0, 0);
                acc[mf * 3 + 1] = __builtin_amdgcn_mfma_f32_16x16x32_bf16(a, wr[ks * 3 + 1], acc[mf * 3 + 1], 0, 0, 0);
                acc[mf * 3 + 2] = __builtin_amdgcn_mfma_f32_16x16x32_bf16(a, wr[ks * 3 + 2], acc[mf * 3 + 2], 0, 0, 0);
            }
        }
        __syncthreads();

        if (t < 15) {
            #pragma unroll
            for (int i = 0; i < 6; ++i) wr[i] = wn[i];
        }
    }

    #pragma unroll
    for (int mf = 0; mf < 2; ++mf) {
        #pragma unroll
        for (int nf = 0; nf < 3; ++nf) {
            const int n = wv * 48 + nf * 16 + qr;
            const int wsel = n >> 6, h = n & 63;
            unsigned short* out = (wsel == 0) ? qw : (wsel == 1) ? kw : vw;
            const f32x4 ov = acc[mf * 3 + nf];
            #pragma unroll
            for (int r = 0; r < 4; ++r)
                out[(size_t)(rb + mf * 16 + 4 * g + r) * Hh + h] = f2b(ov[r]);
        }
    }
}

// ---------------- Kernel 2: flash attention partials (round-5 base + trims) ----------------
// grid (NQ, NC, B). K/V reg-prefetched one tile ahead. Softmax: exp handles
// -inf natively (mc clamp), rescale skipped via wave vote when no row max grew.
#define XSTR 72
#define VSTR 40
__global__ __launch_bounds__(256) void attn_kernel(
    const unsigned short* __restrict__ qw, const unsigned short* __restrict__ kw,
    const unsigned short* __restrict__ vw,
    float* __restrict__ part_O, float* __restrict__ part_ml)
{
    __shared__ unsigned short ks_s[32 * XSTR];
    __shared__ unsigned short vt_s[64 * VSTR];

    const int qt = (NQ - 1) - blockIdx.x;   // big q-tiles dispatched first
    const int ci = blockIdx.y;
    const int b  = blockIdx.z;
    const int tid = threadIdx.x;
    const int wv = tid >> 6, lane = tid & 63;
    const int qr = lane & 15, g = lane >> 4;

    const int ntk = 2 * qt + 2;                    // causal key tiles of 32
    const int tpc = (ntk + NC - 1) / NC;
    const int t0  = ci * tpc;
    const int t1  = (ntk < t0 + tpc) ? ntk : (t0 + tpc);

    const size_t base = (size_t)b * Tlen * Hh;
    const int qrow = qt * 64 + wv * 16 + qr;

    const bf16x8 qf0 = *(const bf16x8*)(qw + base + (size_t)qrow * Hh + 8 * g);
    const bf16x8 qf1 = *(const bf16x8*)(qw + base + (size_t)qrow * Hh + 32 + 8 * g);

    f32x4 o0 = {}, o1 = {}, o2 = {}, o3 = {};
    float m = -INFINITY, l = 0.f;

    // staging coords + K/V register prefetch one tile ahead
    const int srow = tid >> 3, scg = tid & 7;
    const unsigned short* kbase = kw + base + (size_t)srow * Hh + scg * 8;
    const unsigned short* vbase = vw + base + (size_t)srow * Hh + scg * 8;
    const int ksw = ((scg ^ (srow & 3)) << 3);
    bf16x8 k8 = {}, v8 = {};
    if (t0 < t1) {
        k8 = *(const bf16x8*)(kbase + (size_t)t0 * 32 * Hh);
        v8 = *(const bf16x8*)(vbase + (size_t)t0 * 32 * Hh);
    }

    for (int kt = t0; kt < t1; ++kt) {
        const int j0 = kt * 32;
        __syncthreads();                 // previous tile fully consumed
        {   // write prefetched K/V -> LDS (swizzled)
            *(bf16x8*)(&ks_s[srow * XSTR + ksw]) = k8;
            #pragma unroll
            for (int u = 0; u < 8; ++u) {
                const int c = scg * 8 + u;
                const int jx = srow ^ (((c >> 3) & 3) << 3);
                vt_s[c * VSTR + jx] = ((const unsigned short*)&v8)[u];
            }
        }
        __syncthreads();

        // issue next tile's loads (a full tile of compute to hide under)
        if (kt + 1 < t1) {
            k8 = *(const bf16x8*)(kbase + (size_t)(kt + 1) * 32 * Hh);
            v8 = *(const bf16x8*)(vbase + (size_t)(kt + 1) * 32 * Hh);
        }

        // S^T = K . Q^T
        f32x4 a0 = {}, a1 = {};
        {
            const int sw = (g ^ (qr & 3)) << 3;
            bf16x8 kf;
            kf = *(const bf16x8*)(&ks_s[qr * XSTR + sw]);
            a0 = __builtin_amdgcn_mfma_f32_16x16x32_bf16(kf, qf0, a0, 0, 0, 0);
            kf = *(const bf16x8*)(&ks_s[qr * XSTR + 32 + sw]);
            a0 = __builtin_amdgcn_mfma_f32_16x16x32_bf16(kf, qf1, a0, 0, 0, 0);
            kf = *(const bf16x8*)(&ks_s[(16 + qr) * XSTR + sw]);
            a1 = __builtin_amdgcn_mfma_f32_16x16x32_bf16(kf, qf0, a1, 0, 0, 0);
            kf = *(const bf16x8*)(&ks_s[(16 + qr) * XSTR + 32 + sw]);
            a1 = __builtin_amdgcn_mfma_f32_16x16x32_bf16(kf, qf1, a1, 0, 0, 0);
        }

        // masked scores + online softmax
        float p[8];
        float tm = -INFINITY;
        #pragma unroll
        for (int jf = 0; jf < 2; ++jf) {
            #pragma unroll
            for (int r = 0; r < 4; ++r) {
                const int jg = j0 + jf * 16 + 4 * g + r;
                float s = ((jf == 0) ? a0[r] : a1[r]) * 0.125f;
                s = (jg > qrow) ? -INFINITY : s;
                p[jf * 4 + r] = s;
                tm = fmaxf(tm, s);
            }
        }
        tm = fmaxf(tm, __shfl_xor(tm, 16));
        tm = fmaxf(tm, __shfl_xor(tm, 32));
        const float mnew = fmaxf(m, tm);
        const float mc   = fmaxf(mnew, -1e30f);   // -inf-safe exp argument
        float psum = 0.f;
        #pragma unroll
        for (int i = 0; i < 8; ++i) {
            const float pv = __expf(p[i] - mc);   // exp(-inf)=0 handles masks
            p[i] = pv; psum += pv;
        }
        psum += __shfl_xor(psum, 16);
        psum += __shfl_xor(psum, 32);

        if (!__all(tm <= m)) {
            // some row's max grew: rescale O and l
            const float alpha = (m == -INFINITY) ? 0.f : __expf(m - mc);
            const float ar0 = __shfl(alpha, 4 * g + 0);
            const float ar1 = __shfl(alpha, 4 * g + 1);
            const float ar2 = __shfl(alpha, 4 * g + 2);
            const float ar3 = __shfl(alpha, 4 * g + 3);
            o0[0] *= ar0; o0[1] *= ar1; o0[2] *= ar2; o0[3] *= ar3;
            o1[0] *= ar0; o1[1] *= ar1; o1[2] *= ar2; o1[3] *= ar3;
            o2[0] *= ar0; o2[1] *= ar1; o2[2] *= ar2; o2[3] *= ar3;
            o3[0] *= ar0; o3[1] *= ar1; o3[2] *= ar2; o3[3] *= ar3;
            l = l * alpha + psum;
        } else {
            l += psum;                    // alpha == 1 for every row
        }
        m = mnew;

        // repack P -> PV A-fragment
        unsigned pw[4];
        pw[0] = f2b(p[0]) | ((unsigned)f2b(p[1]) << 16);
        pw[1] = f2b(p[2]) | ((unsigned)f2b(p[3]) << 16);
        pw[2] = f2b(p[4]) | ((unsigned)f2b(p[5]) << 16);
        pw[3] = f2b(p[6]) | ((unsigned)f2b(p[7]) << 16);
        union PU { unsigned u[4]; bf16x8 v; } pu;
        #pragma unroll
        for (int w = 0; w < 4; ++w) {
            const int gp  = 2 * g + (w >> 1);
            const int src = 16 * (gp & 3) + qr;
            const unsigned t0s = __shfl(pw[0 + (w & 1)], src);
            const unsigned t1s = __shfl(pw[2 + (w & 1)], src);
            pu.u[w] = (gp & 4) ? t1s : t0s;
        }
        const bf16x8 pa = pu.v;

        // O += P . V
        {
            int cb = qr;
            bf16x8 vf = *(const bf16x8*)(&vt_s[cb * VSTR + 8 * (g ^ ((cb >> 3) & 3))]);
            o0 = __builtin_amdgcn_mfma_f32_16x16x32_bf16(pa, vf, o0, 0, 0, 0);
            cb = 16 + qr;
            vf = *(const bf16x8*)(&vt_s[cb * VSTR + 8 * (g ^ ((cb >> 3) & 3))]);
            o1 = __builtin_amdgcn_mfma_f32_16x16x32_bf16(pa, vf, o1, 0, 0, 0);
            cb = 32 + qr;
            vf = *(const bf16x8*)(&vt_s[cb * VSTR + 8 * (g ^ ((cb >> 3) & 3))]);
            o2 = __builtin_amdgcn_mfma_f32_16x16x32_bf16(pa, vf, o2, 0, 0, 0);
            cb = 48 + qr;
            vf = *(const bf16x8*)(&vt_s[cb * VSTR + 8 * (g ^ ((cb >> 3) & 3))]);
            o3 = __builtin_amdgcn_mfma_f32_16x16x32_bf16(pa, vf, o3, 0, 0, 0);
        }
    }

    // write partials (unnormalized O', m, l)
    const int blin = (b * NQ + qt) * NC + ci;
    float* po = part_O + (size_t)blin * 4096;
    #pragma unroll
    for (int nf = 0; nf < 4; ++nf) {
        const f32x4 ov = (nf == 0) ? o0 : (nf == 1) ? o1 : (nf == 2) ? o2 : o3;
        #pragma unroll
        for (int r = 0; r < 4; ++r)
            po[(size_t)(wv * 16 + 4 * g + r) * 64 + nf * 16 + qr] = ov[r];
    }
    if (g == 0) {
        part_ml[(size_t)blin * 128 + wv * 16 + qr]      = m;
        part_ml[(size_t)blin * 128 + 64 + wv * 16 + qr] = l;
    }
}

// ---------------- Kernel 3: merge partials ----------------
__global__ __launch_bounds__(256) void merge_kernel(
    const float* __restrict__ part_O, const float* __restrict__ part_ml,
    float* __restrict__ out)
{
    const int idx = blockIdx.x * 256 + threadIdx.x;   // 0 .. 524287
    const int row = idx >> 6;
    const int c   = idx & 63;
    const int b   = row >> 11;
    const int t   = row & 2047;
    const int qt  = t >> 6;
    const int qq  = t & 63;
    const int bl0 = (b * NQ + qt) * NC;

    float M = -INFINITY;
    #pragma unroll
    for (int i = 0; i < NC; ++i) {
        const float lvi = part_ml[(size_t)(bl0 + i) * 128 + 64 + qq];
        if (lvi > 0.f) M = fmaxf(M, part_ml[(size_t)(bl0 + i) * 128 + qq]);
    }
    float num = 0.f, den = 0.f;
    #pragma unroll
    for (int i = 0; i < NC; ++i) {
        const float lvi = part_ml[(size_t)(bl0 + i) * 128 + 64 + qq];
        if (lvi > 0.f) {
            const float wgt = __expf(part_ml[(size_t)(bl0 + i) * 128 + qq] - M);
            num += wgt * part_O[(size_t)(bl0 + i) * 4096 + (size_t)qq * 64 + c];
            den += wgt * lvi;
        }
    }
    out[(size_t)row * 64 + c] = num / den;
}

extern "C" void kernel_launch(void* const* d_in, const int* in_sizes, int n_in,
                              void* d_out, int out_size, void* d_ws, size_t ws_size,
                              hipStream_t stream) {
    const float* x  = (const float*)d_in[0];
    const float* Wq = (const float*)d_in[1];
    const float* Wk = (const float*)d_in[2];
    const float* Wv = (const float*)d_in[3];
    float* outp = (float*)d_out;

    unsigned short* wfrag = (unsigned short*)d_ws;      // 192*1024 bf16
    unsigned short* qw = wfrag + 192 * 1024;            // 8192*64 each
    unsigned short* kw = qw + NROWS * Hh;
    unsigned short* vw = kw + NROWS * Hh;
    float* part_O  = (float*)(vw + NROWS * Hh);         // (Bb*NQ*NC) * 4096
    float* part_ml = part_O + (size_t)(Bb * NQ * NC) * 4096;

    wtrans_kernel<<<dim3(96), 256, 0, stream>>>(Wq, Wk, Wv, wfrag);
    proj_kernel<<<dim3(NROWS / 32), 256, 0, stream>>>(x, wfrag, qw, kw, vw);
    attn_kernel<<<dim3(NQ, NC, Bb), 256, 0, stream>>>(qw, kw, vw, part_O, part_ml);
    merge_kernel<<<dim3((NROWS * Hh) / 256), 256, 0, stream>>>(part_O, part_ml, outp);
}